// Round 3
// baseline (478.695 us; speedup 1.0000x reference)
//
#include <hip/hip_runtime.h>

#define NROWS 8192
#define DIM 512
#define HID 1024
#define BN_EPS 1e-5f

typedef unsigned short ushort_t;
typedef __attribute__((ext_vector_type(8))) __bf16 bf16x8;
typedef __attribute__((ext_vector_type(4))) float f32x4;

union U4 {
    uint4 u;
    bf16x8 b;
    ushort_t s[8];
};

static __device__ __forceinline__ float b2f(ushort_t u) {
    union { float f; unsigned int i; } c;
    c.i = ((unsigned int)u) << 16;
    return c.f;
}

static __device__ __forceinline__ ushort_t f2b(float f) {
    union { float f; unsigned int i; } c;
    c.f = f;
    unsigned int i = c.i;
    unsigned int r = (i + 0x7FFFu + ((i >> 16) & 1u)) >> 16;
    return (ushort_t)r;
}

// ---------------------------------------------------------------------------
// 1) column-sum of h: hs[d] = sum_n h[n,d]   (hs pre-zeroed by memset)
// grid 256 x 256; each block covers 32 rows.
__global__ void colsum_kernel(const float* __restrict__ h, float* __restrict__ hs) {
    int t = threadIdx.x;
    int col0 = (t & 127) * 4;
    int rsub = t >> 7;
    int row0 = blockIdx.x * 32;
    float acc[4] = {0.f, 0.f, 0.f, 0.f};
    for (int r = 0; r < 16; ++r) {
        int row = row0 + r * 2 + rsub;
        float4 v = *(const float4*)(h + (size_t)row * DIM + col0);
        acc[0] += v.x; acc[1] += v.y; acc[2] += v.z; acc[3] += v.w;
    }
#pragma unroll
    for (int j = 0; j < 4; ++j) atomicAdd(&hs[col0 + j], acc[j]);
}

// ---------------------------------------------------------------------------
// 2) matvec: outv[col] = sum_{k<512} xin[k]*W[k*ncols+col] + scaleB*bvec[col]
// grid (ncols/32) x 256.
__global__ void matvec_kernel(const float* __restrict__ xin, const float* __restrict__ W,
                              const float* __restrict__ bvec, float scaleB,
                              float* __restrict__ outv, int ncols) {
    __shared__ float red[8][32];
    int t = threadIdx.x;
    int col = blockIdx.x * 32 + (t & 31);
    int ks = t >> 5;
    float s = 0.f;
    for (int ki = 0; ki < 64; ++ki) {
        int k = ks * 64 + ki;
        s += xin[k] * W[(size_t)k * ncols + col];
    }
    red[ks][t & 31] = s;
    __syncthreads();
    if (ks == 0) {
        float tot = scaleB * bvec[col];
#pragma unroll
        for (int r = 0; r < 8; ++r) tot += red[r][t & 31];
        outv[col] = tot;
    }
}

// ---------------------------------------------------------------------------
// 3) per-column constants.  1 block x 512.
__global__ void prep_const_kernel(const float* __restrict__ tvec,
                                  const float* g1, const float* b1,
                                  const float* m1, const float* v1,
                                  const float* g2, const float* b2,
                                  const float* m2, const float* v2,
                                  float* __restrict__ p, float* __restrict__ q0,
                                  float* __restrict__ a2v, float* __restrict__ c2v) {
    int d = threadIdx.x;
    float a1 = g1[d] * rsqrtf(v1[d] + BN_EPS);
    float c1 = b1[d] - m1[d] * a1;
    p[d] = a1;
    q0[d] = tvec[d] * a1 + c1;
    float a2 = g2[d] * rsqrtf(v2[d] + BN_EPS);
    a2v[d] = a2;
    c2v[d] = b2[d] - m2[d] * a2;
}

// ---------------------------------------------------------------------------
// 4a) scale-transpose: out[c][r] = bf16(p[r] * in[r][c]).  in fp32 [R][C].
// grid (C/32, R/32) x 256.
__global__ void scaleT_kernel(const float* __restrict__ in, const float* __restrict__ p,
                              ushort_t* __restrict__ out, int R, int C) {
    __shared__ float tile[32][33];
    int tx = threadIdx.x & 31, ty = threadIdx.x >> 5;
    int bx = blockIdx.x * 32, by = blockIdx.y * 32;
#pragma unroll
    for (int i = 0; i < 32; i += 8)
        tile[ty + i][tx] = in[(size_t)(by + ty + i) * C + bx + tx];
    __syncthreads();
#pragma unroll
    for (int i = 0; i < 32; i += 8)
        out[(size_t)(bx + ty + i) * R + by + tx] = f2b(tile[tx][ty + i] * p[by + tx]);
}

// 4b) plain transpose fp32 [R][C] -> bf16 [C][R].
__global__ void transpose_kernel(const float* __restrict__ in, ushort_t* __restrict__ out,
                                 int R, int C) {
    __shared__ float tile[32][33];
    int tx = threadIdx.x & 31, ty = threadIdx.x >> 5;
    int bx = blockIdx.x * 32, by = blockIdx.y * 32;
#pragma unroll
    for (int i = 0; i < 32; i += 8)
        tile[ty + i][tx] = in[(size_t)(by + ty + i) * C + bx + tx];
    __syncthreads();
#pragma unroll
    for (int i = 0; i < 32; i += 8)
        out[(size_t)(bx + ty + i) * R + by + tx] = f2b(tile[tx][ty + i]);
}

// ---------------------------------------------------------------------------
// 5) GEMM1: Z[8192][1024] = relu( bf16(h) @ W1T^T + b1P ),  h fp32 [8192][512],
// W1T bf16 [1024][512] (pre-scaled by p).  128x128 tile, BK=32, 4 waves.
__global__ __launch_bounds__(256) void gemm1_kernel(const float* __restrict__ A,
                                                    const ushort_t* __restrict__ BT,
                                                    const float* __restrict__ bias,
                                                    ushort_t* __restrict__ C) {
    const int K = DIM, Nn = HID, BK = 32, LDA = BK + 8;
    __shared__ ushort_t As[128 * LDA];
    __shared__ ushort_t Bs[128 * LDA];
    int tid = threadIdx.x;
    int lane = tid & 63, w = tid >> 6;
    int wm = (w & 1) * 64, wn = (w >> 1) * 64;
    int bm = blockIdx.y * 128, bn = blockIdx.x * 128;

    f32x4 acc[4][4] = {};

    int ra = tid >> 1, kca = (tid & 1) * 16;   // A: 128 rows x 32 cols fp32->bf16
    int r0 = tid >> 2, kc0 = (tid & 3) * 8;    // B: 128 rows x 32 cols bf16
    int r1 = r0 + 64;

    for (int k0 = 0; k0 < K; k0 += BK) {
        __syncthreads();
        const float* ap = A + (size_t)(bm + ra) * K + k0 + kca;
        float4 fa = *(const float4*)(ap + 0);
        float4 fb = *(const float4*)(ap + 4);
        float4 fc = *(const float4*)(ap + 8);
        float4 fd = *(const float4*)(ap + 12);
        uint4 b0 = *(const uint4*)(BT + (size_t)(bn + r0) * K + k0 + kc0);
        uint4 b1 = *(const uint4*)(BT + (size_t)(bn + r1) * K + k0 + kc0);
        ushort_t av[16];
        av[0] = f2b(fa.x); av[1] = f2b(fa.y); av[2] = f2b(fa.z); av[3] = f2b(fa.w);
        av[4] = f2b(fb.x); av[5] = f2b(fb.y); av[6] = f2b(fb.z); av[7] = f2b(fb.w);
        av[8] = f2b(fc.x); av[9] = f2b(fc.y); av[10] = f2b(fc.z); av[11] = f2b(fc.w);
        av[12] = f2b(fd.x); av[13] = f2b(fd.y); av[14] = f2b(fd.z); av[15] = f2b(fd.w);
        *(uint4*)(As + ra * LDA + kca) = *(uint4*)(av);
        *(uint4*)(As + ra * LDA + kca + 8) = *(uint4*)(av + 8);
        *(uint4*)(Bs + r0 * LDA + kc0) = b0;
        *(uint4*)(Bs + r1 * LDA + kc0) = b1;
        __syncthreads();

        int koff = (lane >> 4) * 8;
        bf16x8 af[4], bfr[4];
#pragma unroll
        for (int i = 0; i < 4; ++i) {
            U4 t;
            t.u = *(const uint4*)(As + (wm + i * 16 + (lane & 15)) * LDA + koff);
            af[i] = t.b;
        }
#pragma unroll
        for (int j = 0; j < 4; ++j) {
            U4 t;
            t.u = *(const uint4*)(Bs + (wn + j * 16 + (lane & 15)) * LDA + koff);
            bfr[j] = t.b;
        }
#pragma unroll
        for (int i = 0; i < 4; ++i)
#pragma unroll
            for (int j = 0; j < 4; ++j)
                acc[i][j] = __builtin_amdgcn_mfma_f32_16x16x32_bf16(af[i], bfr[j], acc[i][j], 0, 0, 0);
    }

#pragma unroll
    for (int i = 0; i < 4; ++i) {
        int row0 = bm + wm + i * 16 + (lane >> 4) * 4;
#pragma unroll
        for (int j = 0; j < 4; ++j) {
            int col = bn + wn + j * 16 + (lane & 15);
            float bv = bias[col];
#pragma unroll
            for (int r = 0; r < 4; ++r) {
                float v = fmaxf(acc[i][j][r] + bv, 0.f);
                C[(size_t)(row0 + r) * Nn + col] = f2b(v);
            }
        }
    }
}

// ---------------------------------------------------------------------------
// 6) GEMM2 + fused epilogue:
// out[n][d] = ((h[n][d]*p[d]+q0[d]) + (Z @ W2T^T)[n][d] + f2b[d]) * a2[d] + c2[d]
// Z bf16 [8192][1024], W2T bf16 [512][1024].  128x64 tile, BK=32, 4 waves
// (2x2 of 64x32 wave tiles), grid (8, 64) = 512 blocks.
__global__ __launch_bounds__(256) void gemm2_kernel(const ushort_t* __restrict__ A,
                                                    const ushort_t* __restrict__ BT,
                                                    const float* __restrict__ bias,
                                                    const float* __restrict__ h,
                                                    const float* __restrict__ p,
                                                    const float* __restrict__ q0,
                                                    const float* __restrict__ a2v,
                                                    const float* __restrict__ c2v,
                                                    float* __restrict__ out) {
    const int K = HID, BK = 32, LDA = BK + 8;
    __shared__ ushort_t As[128 * LDA];
    __shared__ ushort_t Bs[64 * LDA];
    int tid = threadIdx.x;
    int lane = tid & 63, w = tid >> 6;
    int wm = (w & 1) * 64, wn = (w >> 1) * 32;
    int bm = blockIdx.y * 128, bn = blockIdx.x * 64;

    f32x4 acc[4][2] = {};

    int r0 = tid >> 2, kc0 = (tid & 3) * 8;   // A rows 0..63 / B rows 0..63
    int r1 = r0 + 64;                          // A rows 64..127

    for (int k0 = 0; k0 < K; k0 += BK) {
        __syncthreads();
        uint4 a0 = *(const uint4*)(A + (size_t)(bm + r0) * K + k0 + kc0);
        uint4 a1 = *(const uint4*)(A + (size_t)(bm + r1) * K + k0 + kc0);
        uint4 bb = *(const uint4*)(BT + (size_t)(bn + r0) * K + k0 + kc0);
        *(uint4*)(As + r0 * LDA + kc0) = a0;
        *(uint4*)(As + r1 * LDA + kc0) = a1;
        *(uint4*)(Bs + r0 * LDA + kc0) = bb;
        __syncthreads();

        int koff = (lane >> 4) * 8;
        bf16x8 af[4], bfr[2];
#pragma unroll
        for (int i = 0; i < 4; ++i) {
            U4 t;
            t.u = *(const uint4*)(As + (wm + i * 16 + (lane & 15)) * LDA + koff);
            af[i] = t.b;
        }
#pragma unroll
        for (int j = 0; j < 2; ++j) {
            U4 t;
            t.u = *(const uint4*)(Bs + (wn + j * 16 + (lane & 15)) * LDA + koff);
            bfr[j] = t.b;
        }
#pragma unroll
        for (int i = 0; i < 4; ++i)
#pragma unroll
            for (int j = 0; j < 2; ++j)
                acc[i][j] = __builtin_amdgcn_mfma_f32_16x16x32_bf16(af[i], bfr[j], acc[i][j], 0, 0, 0);
    }

#pragma unroll
    for (int i = 0; i < 4; ++i) {
        int row0 = bm + wm + i * 16 + (lane >> 4) * 4;
#pragma unroll
        for (int j = 0; j < 2; ++j) {
            int col = bn + wn + j * 16 + (lane & 15);
            float bv = bias[col], pp = p[col], qq = q0[col];
            float aa = a2v[col], cc = c2v[col];
#pragma unroll
            for (int r = 0; r < 4; ++r) {
                int row = row0 + r;
                float x1 = h[(size_t)row * DIM + col] * pp + qq;
                out[(size_t)row * DIM + col] = (x1 + acc[i][j][r] + bv) * aa + cc;
            }
        }
    }
}

// ---------------------------------------------------------------------------
extern "C" void kernel_launch(void* const* d_in, const int* in_sizes, int n_in,
                              void* d_out, int out_size, void* d_ws, size_t ws_size,
                              hipStream_t stream) {
    // inputs (all fp32): 0:A 1:h 2:qw 3:qb 4:kw 5:kb 6:vw 7:vb 8:ow 9:ob
    // 10:f1w 11:f1b 12:f2w 13:f2b 14-17:bn1 g,b,m,v 18-21:bn2 g,b,m,v
    const float* h = (const float*)d_in[1];
    const float* vw = (const float*)d_in[6];
    const float* vb = (const float*)d_in[7];
    const float* ow = (const float*)d_in[8];
    const float* ob = (const float*)d_in[9];
    const float* f1w = (const float*)d_in[10];
    const float* f1b = (const float*)d_in[11];
    const float* f2w = (const float*)d_in[12];
    const float* fb2 = (const float*)d_in[13];
    const float* g1 = (const float*)d_in[14];
    const float* b1 = (const float*)d_in[15];
    const float* m1 = (const float*)d_in[16];
    const float* v1 = (const float*)d_in[17];
    const float* g2 = (const float*)d_in[18];
    const float* b2 = (const float*)d_in[19];
    const float* m2 = (const float*)d_in[20];
    const float* v2 = (const float*)d_in[21];
    float* out = (float*)d_out;

    char* ws = (char*)d_ws;
    float* hs = (float*)(ws + 0);              // 512 f32
    float* pC = (float*)(ws + 2048);           // 512 f32
    float* q0C = (float*)(ws + 4096);          // 512 f32
    float* a2C = (float*)(ws + 6144);          // 512 f32
    float* c2C = (float*)(ws + 8192);          // 512 f32
    float* sBuf = (float*)(ws + 10240);        // 512 f32
    float* tBuf = (float*)(ws + 12288);        // 512 f32
    float* b1P = (float*)(ws + 16384);         // 1024 f32
    ushort_t* W1T = (ushort_t*)(ws + 32768);               // [1024][512] bf16, 1 MB
    ushort_t* W2T = (ushort_t*)(ws + 32768 + 1048576);     // [512][1024] bf16, 1 MB
    ushort_t* Z = (ushort_t*)(ws + 32768 + 2097152);       // [8192][1024] bf16, 16 MB

    hipMemsetAsync(hs, 0, 512 * sizeof(float), stream);
    colsum_kernel<<<256, 256, 0, stream>>>(h, hs);
    matvec_kernel<<<16, 256, 0, stream>>>(hs, vw, vb, 8192.0f, sBuf, 512);
    matvec_kernel<<<16, 256, 0, stream>>>(sBuf, ow, ob, 1.0f, tBuf, 512);
    prep_const_kernel<<<1, 512, 0, stream>>>(tBuf, g1, b1, m1, v1, g2, b2, m2, v2,
                                             pC, q0C, a2C, c2C);
    matvec_kernel<<<32, 256, 0, stream>>>(q0C, f1w, f1b, 1.0f, b1P, 1024);
    scaleT_kernel<<<dim3(32, 16), 256, 0, stream>>>(f1w, pC, W1T, 512, 1024);
    transpose_kernel<<<dim3(16, 32), 256, 0, stream>>>(f2w, W2T, 1024, 512);
    gemm1_kernel<<<dim3(8, 64), 256, 0, stream>>>(h, W1T, b1P, Z);
    gemm2_kernel<<<dim3(8, 64), 256, 0, stream>>>(Z, W2T, fb2, h, pC, q0C, a2C, c2C, out);
}

// Round 4
// 471.079 us; speedup vs baseline: 1.0162x; 1.0162x over previous
//
#include <hip/hip_runtime.h>

#define NROWS 8192
#define DIM 512
#define HID 1024
#define BN_EPS 1e-5f

typedef unsigned short ushort_t;
typedef __attribute__((ext_vector_type(8))) __bf16 bf16x8;
typedef __attribute__((ext_vector_type(4))) float f32x4;

union U4 {
    uint4 u;
    bf16x8 b;
    ushort_t s[8];
};

static __device__ __forceinline__ float b2f(ushort_t u) {
    union { float f; unsigned int i; } c;
    c.i = ((unsigned int)u) << 16;
    return c.f;
}

static __device__ __forceinline__ ushort_t f2b(float f) {
    union { float f; unsigned int i; } c;
    c.f = f;
    unsigned int i = c.i;
    unsigned int r = (i + 0x7FFFu + ((i >> 16) & 1u)) >> 16;
    return (ushort_t)r;
}

// ---------------------------------------------------------------------------
// 1) colsum + convert: hs[d] += sum_n h[n,d]; hB = bf16(h).
// grid 256 x 256; each block covers 32 rows. hs pre-zeroed by memset.
__global__ void colsum_convert_kernel(const float* __restrict__ h, float* __restrict__ hs,
                                      ushort_t* __restrict__ hB) {
    int t = threadIdx.x;
    int col0 = (t & 127) * 4;
    int rsub = t >> 7;
    int row0 = blockIdx.x * 32;
    float acc[4] = {0.f, 0.f, 0.f, 0.f};
    for (int r = 0; r < 16; ++r) {
        int row = row0 + r * 2 + rsub;
        float4 v = *(const float4*)(h + (size_t)row * DIM + col0);
        acc[0] += v.x; acc[1] += v.y; acc[2] += v.z; acc[3] += v.w;
        ushort_t bv[4];
        bv[0] = f2b(v.x); bv[1] = f2b(v.y); bv[2] = f2b(v.z); bv[3] = f2b(v.w);
        *(uint2*)(hB + (size_t)row * DIM + col0) = *(uint2*)bv;
    }
#pragma unroll
    for (int j = 0; j < 4; ++j) atomicAdd(&hs[col0 + j], acc[j]);
}

// ---------------------------------------------------------------------------
// 2) matvec: outv[col] = sum_{k<512} xin[k]*W[k*ncols+col] + scaleB*bvec[col]
// grid (ncols/32) x 256.
__global__ void matvec_kernel(const float* __restrict__ xin, const float* __restrict__ W,
                              const float* __restrict__ bvec, float scaleB,
                              float* __restrict__ outv, int ncols) {
    __shared__ float red[8][32];
    int t = threadIdx.x;
    int col = blockIdx.x * 32 + (t & 31);
    int ks = t >> 5;
    float s = 0.f;
    for (int ki = 0; ki < 64; ++ki) {
        int k = ks * 64 + ki;
        s += xin[k] * W[(size_t)k * ncols + col];
    }
    red[ks][t & 31] = s;
    __syncthreads();
    if (ks == 0) {
        float tot = scaleB * bvec[col];
#pragma unroll
        for (int r = 0; r < 8; ++r) tot += red[r][t & 31];
        outv[col] = tot;
    }
}

// ---------------------------------------------------------------------------
// 2b) b1P[col] = f1b[col] + sum_k q0[k]*f1w[k*1024+col],
//     q0[k] = t[k]*a1[k] + (b1[k] - m1[k]*a1[k]), a1 = g1*rsqrt(v1+eps).
// grid 32 x 256.
__global__ void matvec_b1p_kernel(const float* __restrict__ tvec,
                                  const float* __restrict__ g1, const float* __restrict__ b1,
                                  const float* __restrict__ m1, const float* __restrict__ v1,
                                  const float* __restrict__ W, const float* __restrict__ bvec,
                                  float* __restrict__ outv) {
    __shared__ float red[8][32];
    int t = threadIdx.x;
    int col = blockIdx.x * 32 + (t & 31);
    int ks = t >> 5;
    float s = 0.f;
    for (int ki = 0; ki < 64; ++ki) {
        int k = ks * 64 + ki;
        float a1 = g1[k] * rsqrtf(v1[k] + BN_EPS);
        float q0 = tvec[k] * a1 + (b1[k] - m1[k] * a1);
        s += q0 * W[(size_t)k * HID + col];
    }
    red[ks][t & 31] = s;
    __syncthreads();
    if (ks == 0) {
        float tot = bvec[col];
#pragma unroll
        for (int r = 0; r < 8; ++r) tot += red[r][t & 31];
        outv[col] = tot;
    }
}

// ---------------------------------------------------------------------------
// 3) combined weight prep (1024 blocks x 256):
//  b < 512 : W1T[c][r] = bf16(f1w[r][c] * a1[r]),  f1w [512][1024]
//  b >= 512: W2T[c][r] = bf16(f2w[r][c]),          f2w [1024][512]
__global__ void prepw_kernel(const float* __restrict__ f1w,
                             const float* __restrict__ g1, const float* __restrict__ v1,
                             const float* __restrict__ f2w,
                             ushort_t* __restrict__ W1T, ushort_t* __restrict__ W2T) {
    __shared__ float tile[32][33];
    int tx = threadIdx.x & 31, ty = threadIdx.x >> 5;
    int b = blockIdx.x;
    if (b < 512) {
        int bx = (b & 31) * 32, by = (b >> 5) * 32;   // bx: col of f1w (C=1024), by: row (R=512)
#pragma unroll
        for (int i = 0; i < 32; i += 8)
            tile[ty + i][tx] = f1w[(size_t)(by + ty + i) * HID + bx + tx];
        __syncthreads();
        int r = by + tx;
        float a1 = g1[r] * rsqrtf(v1[r] + BN_EPS);
#pragma unroll
        for (int i = 0; i < 32; i += 8)
            W1T[(size_t)(bx + ty + i) * DIM + r] = f2b(tile[tx][ty + i] * a1);
    } else {
        int b2 = b - 512;
        int bx = (b2 & 15) * 32, by = (b2 >> 4) * 32; // bx: col of f2w (C=512), by: row (R=1024)
#pragma unroll
        for (int i = 0; i < 32; i += 8)
            tile[ty + i][tx] = f2w[(size_t)(by + ty + i) * DIM + bx + tx];
        __syncthreads();
#pragma unroll
        for (int i = 0; i < 32; i += 8)
            W2T[(size_t)(bx + ty + i) * HID + by + tx] = f2b(tile[tx][ty + i]);
    }
}

// ---------------------------------------------------------------------------
// 4) GEMM1: Z = relu(hB @ W1T^T + b1P).  All bf16, bias fp32.
// 128x128 tile, BK=32, 256 threads = 4 waves, each wave 4x4 of 16x16x32 MFMA.
__global__ __launch_bounds__(256) void gemm1_kernel(const ushort_t* __restrict__ A,
                                                    const ushort_t* __restrict__ BT,
                                                    const float* __restrict__ bias,
                                                    ushort_t* __restrict__ C) {
    const int K = DIM, Nn = HID, BK = 32, LDA = BK + 8;
    __shared__ ushort_t As[128 * LDA];
    __shared__ ushort_t Bs[128 * LDA];
    int tid = threadIdx.x;
    int lane = tid & 63, w = tid >> 6;
    int wm = (w & 1) * 64, wn = (w >> 1) * 64;
    int bm = blockIdx.y * 128, bn = blockIdx.x * 128;

    f32x4 acc[4][4] = {};

    int r0 = tid >> 2, kc0 = (tid & 3) * 8;
    int r1 = r0 + 64;

    for (int k0 = 0; k0 < K; k0 += BK) {
        __syncthreads();
        uint4 a0 = *(const uint4*)(A + (size_t)(bm + r0) * K + k0 + kc0);
        uint4 a1 = *(const uint4*)(A + (size_t)(bm + r1) * K + k0 + kc0);
        uint4 b0 = *(const uint4*)(BT + (size_t)(bn + r0) * K + k0 + kc0);
        uint4 b1 = *(const uint4*)(BT + (size_t)(bn + r1) * K + k0 + kc0);
        *(uint4*)(As + r0 * LDA + kc0) = a0;
        *(uint4*)(As + r1 * LDA + kc0) = a1;
        *(uint4*)(Bs + r0 * LDA + kc0) = b0;
        *(uint4*)(Bs + r1 * LDA + kc0) = b1;
        __syncthreads();

        int koff = (lane >> 4) * 8;
        bf16x8 af[4], bfr[4];
#pragma unroll
        for (int i = 0; i < 4; ++i) {
            U4 t;
            t.u = *(const uint4*)(As + (wm + i * 16 + (lane & 15)) * LDA + koff);
            af[i] = t.b;
        }
#pragma unroll
        for (int j = 0; j < 4; ++j) {
            U4 t;
            t.u = *(const uint4*)(Bs + (wn + j * 16 + (lane & 15)) * LDA + koff);
            bfr[j] = t.b;
        }
#pragma unroll
        for (int i = 0; i < 4; ++i)
#pragma unroll
            for (int j = 0; j < 4; ++j)
                acc[i][j] = __builtin_amdgcn_mfma_f32_16x16x32_bf16(af[i], bfr[j], acc[i][j], 0, 0, 0);
    }

#pragma unroll
    for (int i = 0; i < 4; ++i) {
        int row0 = bm + wm + i * 16 + (lane >> 4) * 4;
#pragma unroll
        for (int j = 0; j < 4; ++j) {
            int col = bn + wn + j * 16 + (lane & 15);
            float bv = bias[col];
#pragma unroll
            for (int r = 0; r < 4; ++r) {
                float v = fmaxf(acc[i][j][r] + bv, 0.f);
                C[(size_t)(row0 + r) * Nn + col] = f2b(v);
            }
        }
    }
}

// ---------------------------------------------------------------------------
// 5) GEMM2 + fused epilogue:
// out[n][d] = ((hB*a1 + q0) + (Z@W2T^T) + f2b) * a2 + c2,  all consts inline.
// 128x64 tile, BK=32, 4 waves (2x2 of 64x32), grid (8, 64).
__global__ __launch_bounds__(256) void gemm2_kernel(const ushort_t* __restrict__ A,
                                                    const ushort_t* __restrict__ BT,
                                                    const float* __restrict__ bias,
                                                    const ushort_t* __restrict__ hB,
                                                    const float* __restrict__ tvec,
                                                    const float* __restrict__ g1,
                                                    const float* __restrict__ b1,
                                                    const float* __restrict__ m1,
                                                    const float* __restrict__ v1,
                                                    const float* __restrict__ g2,
                                                    const float* __restrict__ b2,
                                                    const float* __restrict__ m2,
                                                    const float* __restrict__ v2,
                                                    float* __restrict__ out) {
    const int K = HID, BK = 32, LDA = BK + 8;
    __shared__ ushort_t As[128 * LDA];
    __shared__ ushort_t Bs[64 * LDA];
    int tid = threadIdx.x;
    int lane = tid & 63, w = tid >> 6;
    int wm = (w & 1) * 64, wn = (w >> 1) * 32;
    int bm = blockIdx.y * 128, bn = blockIdx.x * 64;

    f32x4 acc[4][2] = {};

    int r0 = tid >> 2, kc0 = (tid & 3) * 8;
    int r1 = r0 + 64;

    for (int k0 = 0; k0 < K; k0 += BK) {
        __syncthreads();
        uint4 a0 = *(const uint4*)(A + (size_t)(bm + r0) * K + k0 + kc0);
        uint4 a1 = *(const uint4*)(A + (size_t)(bm + r1) * K + k0 + kc0);
        uint4 bb = *(const uint4*)(BT + (size_t)(bn + r0) * K + k0 + kc0);
        *(uint4*)(As + r0 * LDA + kc0) = a0;
        *(uint4*)(As + r1 * LDA + kc0) = a1;
        *(uint4*)(Bs + r0 * LDA + kc0) = bb;
        __syncthreads();

        int koff = (lane >> 4) * 8;
        bf16x8 af[4], bfr[2];
#pragma unroll
        for (int i = 0; i < 4; ++i) {
            U4 t;
            t.u = *(const uint4*)(As + (wm + i * 16 + (lane & 15)) * LDA + koff);
            af[i] = t.b;
        }
#pragma unroll
        for (int j = 0; j < 2; ++j) {
            U4 t;
            t.u = *(const uint4*)(Bs + (wn + j * 16 + (lane & 15)) * LDA + koff);
            bfr[j] = t.b;
        }
#pragma unroll
        for (int i = 0; i < 4; ++i)
#pragma unroll
            for (int j = 0; j < 2; ++j)
                acc[i][j] = __builtin_amdgcn_mfma_f32_16x16x32_bf16(af[i], bfr[j], acc[i][j], 0, 0, 0);
    }

#pragma unroll
    for (int i = 0; i < 4; ++i) {
        int row0 = bm + wm + i * 16 + (lane >> 4) * 4;
#pragma unroll
        for (int j = 0; j < 2; ++j) {
            int col = bn + wn + j * 16 + (lane & 15);
            float a1c = g1[col] * rsqrtf(v1[col] + BN_EPS);
            float q0c = tvec[col] * a1c + (b1[col] - m1[col] * a1c);
            float a2c = g2[col] * rsqrtf(v2[col] + BN_EPS);
            float c2c = b2[col] - m2[col] * a2c;
            float bv = bias[col];
#pragma unroll
            for (int r = 0; r < 4; ++r) {
                int row = row0 + r;
                float x1 = b2f(hB[(size_t)row * DIM + col]) * a1c + q0c;
                out[(size_t)row * DIM + col] = (x1 + acc[i][j][r] + bv) * a2c + c2c;
            }
        }
    }
}

// ---------------------------------------------------------------------------
extern "C" void kernel_launch(void* const* d_in, const int* in_sizes, int n_in,
                              void* d_out, int out_size, void* d_ws, size_t ws_size,
                              hipStream_t stream) {
    // inputs (all fp32): 0:A 1:h 2:qw 3:qb 4:kw 5:kb 6:vw 7:vb 8:ow 9:ob
    // 10:f1w 11:f1b 12:f2w 13:f2b 14-17:bn1 g,b,m,v 18-21:bn2 g,b,m,v
    const float* h = (const float*)d_in[1];
    const float* vw = (const float*)d_in[6];
    const float* vb = (const float*)d_in[7];
    const float* ow = (const float*)d_in[8];
    const float* ob = (const float*)d_in[9];
    const float* f1w = (const float*)d_in[10];
    const float* f1b = (const float*)d_in[11];
    const float* f2w = (const float*)d_in[12];
    const float* fb2 = (const float*)d_in[13];
    const float* g1 = (const float*)d_in[14];
    const float* b1 = (const float*)d_in[15];
    const float* m1 = (const float*)d_in[16];
    const float* v1 = (const float*)d_in[17];
    const float* g2 = (const float*)d_in[18];
    const float* b2 = (const float*)d_in[19];
    const float* m2 = (const float*)d_in[20];
    const float* v2 = (const float*)d_in[21];
    float* out = (float*)d_out;

    char* ws = (char*)d_ws;
    float* hs = (float*)(ws + 0);              // 512 f32
    float* sBuf = (float*)(ws + 4096);         // 512 f32
    float* tBuf = (float*)(ws + 8192);         // 512 f32
    float* b1P = (float*)(ws + 16384);         // 1024 f32
    ushort_t* W1T = (ushort_t*)(ws + 32768);               // [1024][512] bf16, 1 MB
    ushort_t* W2T = (ushort_t*)(ws + 32768 + 1048576);     // [512][1024] bf16, 1 MB
    ushort_t* Z = (ushort_t*)(ws + 32768 + 2097152);       // [8192][1024] bf16, 16 MB
    ushort_t* hB = (ushort_t*)(ws + 32768 + 2097152 + 16777216); // [8192][512] bf16, 8 MB

    hipMemsetAsync(hs, 0, 512 * sizeof(float), stream);
    colsum_convert_kernel<<<256, 256, 0, stream>>>(h, hs, hB);
    matvec_kernel<<<16, 256, 0, stream>>>(hs, vw, vb, 8192.0f, sBuf, 512);
    matvec_kernel<<<16, 256, 0, stream>>>(sBuf, ow, ob, 1.0f, tBuf, 512);
    matvec_b1p_kernel<<<32, 256, 0, stream>>>(tBuf, g1, b1, m1, v1, f1w, f1b, b1P);
    prepw_kernel<<<1024, 256, 0, stream>>>(f1w, g1, v1, f2w, W1T, W2T);
    gemm1_kernel<<<dim3(8, 64), 256, 0, stream>>>(hB, W1T, b1P, Z);
    gemm2_kernel<<<dim3(8, 64), 256, 0, stream>>>(Z, W2T, fb2, hB, tBuf,
                                                  g1, b1, m1, v1, g2, b2, m2, v2, out);
}